// Round 6
// baseline (84.192 us; speedup 1.0000x reference)
//
#include <hip/hip_runtime.h>

// RelationModule, two kernels (R5 cooperative dataflow, kernel-boundary sync):
//   k1: per-wave phi/u (normal orient.), wave M-tile, 4-wave block reduce,
//       block-partial -> d_ws slot (no atomics, no memset; every byte written).
//   k2: redundant per-block reduce of its batch's 16 partials -> M[b] in LDS,
//       then transposed pipeline (C col = element): psi^T/phi^T/u^T, diag via
//       1 shfl, att^T, corr^T, per-wave LDS transpose, out = x + corr (fp32
//       residual exact). Stream order gives cross-XCD visibility.
//
// B=32, N=2048, F=32.  bf16 MFMA v_mfma_f32_32x32x16_bf16 for all contractions.
// Layouts (R4-verified on this problem):
//   C/D 32x32: col = lane&31, row = (reg&3) + 8*(reg>>2) + 4*(lane>>5)
//   A frag:    m = lane&31,  k = 8*(lane>>5) + j      (j=0..7 per 4-VGPR half)
//   B frag:    n = lane&31,  k = 8*(lane>>5) + j

namespace {
constexpr int kF = 32;
constexpr int kN = 2048;
constexpr int kB = 32;
}

typedef __attribute__((ext_vector_type(8))) short bf16x8;
typedef __attribute__((ext_vector_type(16))) float f32x16;

union BF8 { bf16x8 v; int i[4]; };

__device__ inline unsigned short f2bf(float f) {
    union { float f; unsigned int u; } c; c.f = f;
    unsigned int r = c.u + 0x7FFFu + ((c.u >> 16) & 1u);   // RNE
    return (unsigned short)(r >> 16);
}
__device__ inline int pk2(float lo, float hi) {
    return (int)f2bf(lo) | ((int)f2bf(hi) << 16);
}

// Operand frags of Mat (row-major, row stride `ld`): K = Mat rows, lane&31 = col.
// As A: A = Mat^T (m = col).  As B: B = Mat (n = col).  Global or LDS.
__device__ inline void load_wfrags(const float* __restrict__ W, int ld, int col, int h,
                                   bf16x8& f0, bf16x8& f1) {
    BF8 a, b;
#pragma unroll
    for (int q = 0; q < 4; ++q)
        a.i[q] = pk2(W[(8 * h + 2 * q) * ld + col], W[(8 * h + 2 * q + 1) * ld + col]);
#pragma unroll
    for (int q = 0; q < 4; ++q)
        b.i[q] = pk2(W[(16 + 8 * h + 2 * q) * ld + col], W[(16 + 8 * h + 2 * q + 1) * ld + col]);
    f0 = a.v; f1 = b.v;
}

// x operand: element j of fi = x[row][16*fi + 8h + j] (row = this lane's element).
// Same bytes serve A = x (k1) and B = x^T (k2).
__device__ inline void load_xfrags(const float* __restrict__ xr, int h,
                                   bf16x8& f0, bf16x8& f1) {
    float4 a = *(const float4*)(xr + 8 * h);
    float4 b = *(const float4*)(xr + 8 * h + 4);
    float4 c = *(const float4*)(xr + 16 + 8 * h);
    float4 d = *(const float4*)(xr + 16 + 8 * h + 4);
    BF8 u0, u1;
    u0.i[0] = pk2(a.x, a.y); u0.i[1] = pk2(a.z, a.w);
    u0.i[2] = pk2(b.x, b.y); u0.i[3] = pk2(b.z, b.w);
    u1.i[0] = pk2(c.x, c.y); u1.i[1] = pk2(c.z, c.w);
    u1.i[2] = pk2(d.x, d.y); u1.i[3] = pk2(d.z, d.w);
    f0 = u0.v; f1 = u1.v;
}

// C-layout regs -> operand frags with K = C-row (col stays in lanes).
// Packed-pair shfl_xor(32) fills the partner half's rows.
__device__ inline void c_to_kfrags(const f32x16& v, int h, bf16x8& f0, bf16x8& f1) {
    int p[8], t[8];
#pragma unroll
    for (int q = 0; q < 8; ++q) p[q] = pk2(v[2 * q], v[2 * q + 1]);
#pragma unroll
    for (int q = 0; q < 8; ++q) t[q] = __shfl_xor(p[q], 32, 64);
    BF8 a, b;
    a.i[0] = h ? t[2] : p[0];
    a.i[1] = h ? t[3] : p[1];
    a.i[2] = h ? p[2] : t[0];
    a.i[3] = h ? p[3] : t[1];
    b.i[0] = h ? t[6] : p[4];
    b.i[1] = h ? t[7] : p[5];
    b.i[2] = h ? p[6] : t[4];
    b.i[3] = h ? p[7] : t[5];
    f0 = a.v; f1 = b.v;
}

__device__ inline f32x16 zero16() {
    f32x16 z;
#pragma unroll
    for (int i = 0; i < 16; ++i) z[i] = 0.f;
    return z;
}

#define MFMA(A, B, C) __builtin_amdgcn_mfma_f32_32x32x16_bf16(A, B, C, 0, 0, 0)

// ---------------------------------------------------------------------------
// Kernel 1: block-partial M tiles. Grid 512 x 256 (4 waves, 1 batch-slice).
// ---------------------------------------------------------------------------
__global__ __launch_bounds__(256, 2) void k_partial_m(
    const float* __restrict__ x,
    const float* __restrict__ w_phi, const float* __restrict__ b_phi,
    const float* __restrict__ w_u,   const float* __restrict__ b_u,
    float* __restrict__ part)        // [512][1024] fp32, fully overwritten
{
    __shared__ float red_s[4][64 * 20];

    const int tid = threadIdx.x;
    const int lane = tid & 63;
    const int w = tid >> 6;
    const int col = lane & 31;
    const int h = lane >> 5;
    const int blk = blockIdx.x;
    const int row0 = blk * 128 + w * 32;    // 128 | 2048: block stays in-batch

    bf16x8 ax0, ax1;
    load_xfrags(x + (size_t)(row0 + col) * kF, h, ax0, ax1);
    bf16x8 bp0, bp1, bu0, bu1;
    load_wfrags(w_phi, kF, col, h, bp0, bp1);
    load_wfrags(w_u,   kF, col, h, bu0, bu1);

    f32x16 phiC = zero16(), uC = zero16();
    phiC = MFMA(ax0, bp0, phiC); phiC = MFMA(ax1, bp1, phiC);
    uC   = MFMA(ax0, bu0, uC);   uC   = MFMA(ax1, bu1, uC);

    const float bphi = b_phi[col];
    const float bu = b_u[col];
#pragma unroll
    for (int r = 0; r < 16; ++r) {
        phiC[r] += bphi;
        uC[r] = fmaxf(uC[r] + bu, 0.f);
    }

    bf16x8 ap0, ap1, fu0, fu1;
    c_to_kfrags(phiC, h, ap0, ap1);     // A = phi^T (K = element)
    c_to_kfrags(uC, h, fu0, fu1);       // B = u
    f32x16 macc = zero16();
    macc = MFMA(ap0, fu0, macc);
    macc = MFMA(ap1, fu1, macc);        // C: col = g, row = f

    float* rs = red_s[w] + lane * 20;
#pragma unroll
    for (int q = 0; q < 4; ++q)
        *(float4*)(rs + 4 * q) = make_float4(macc[4 * q], macc[4 * q + 1],
                                             macc[4 * q + 2], macc[4 * q + 3]);
    __syncthreads();

    const int lp = tid >> 2;
    const int q = tid & 3;
    float4 s = make_float4(0.f, 0.f, 0.f, 0.f);
#pragma unroll
    for (int ww = 0; ww < 4; ++ww) {
        float4 v = *(const float4*)(red_s[ww] + lp * 20 + 4 * q);
        s.x += v.x; s.y += v.y; s.z += v.z; s.w += v.w;
    }
    // coalesced store in "reduced-C order"; k2 applies the same (lp,q) map
    *(float4*)(part + (size_t)blk * 1024 + tid * 4) = s;
}

// ---------------------------------------------------------------------------
// Kernel 2: per-block M[b] reduce (redundant, cheap, L2/L3-fed) + transposed
// relation pipeline. Grid 512 x 256.
// ---------------------------------------------------------------------------
__global__ __launch_bounds__(256, 2) void k_relation(
    const float* __restrict__ x,
    const float* __restrict__ w_psi, const float* __restrict__ b_psi,
    const float* __restrict__ w_phi, const float* __restrict__ b_phi,
    const float* __restrict__ w_u,   const float* __restrict__ b_u,
    const float* __restrict__ w_r,
    const float* __restrict__ part,  // [512][1024] block partials from k1
    float* __restrict__ out)
{
    __shared__ float t_s[4][32 * 36];   // per-wave transpose scratch
    __shared__ float m_s[kF * 33];      // M[b], row stride 33 (conflict-free)

    const int tid = threadIdx.x;
    const int lane = tid & 63;
    const int w = tid >> 6;
    const int col = lane & 31;
    const int h = lane >> 5;
    const int blk = blockIdx.x;
    const int row0 = blk * 128 + w * 32;
    const int b = blk >> 4;

    // ---- phase 1.5: M[b] = sum of this batch's 16 partials (coalesced) ----
    const float* pb = part + (size_t)(b * 16) * 1024 + tid * 4;
    float4 ms = make_float4(0.f, 0.f, 0.f, 0.f);
#pragma unroll
    for (int p = 0; p < 16; ++p) {
        float4 v = *(const float4*)(pb + p * 1024);
        ms.x += v.x; ms.y += v.y; ms.z += v.z; ms.w += v.w;
    }
    {
        const int lp = tid >> 2;
        const int q = tid & 3;
        const int g = lp & 31;
        const int hp = lp >> 5;
        const int f0 = 8 * q + 4 * hp;  // rows f0..f0+3 (row map, r&3 = 0..3)
        m_s[(f0 + 0) * 33 + g] = ms.x;
        m_s[(f0 + 1) * 33 + g] = ms.y;
        m_s[(f0 + 2) * 33 + g] = ms.z;
        m_s[(f0 + 3) * 33 + g] = ms.w;
    }

    // overlap-friendly: x/W frag builds don't depend on m_s
    bf16x8 ax0, ax1;
    load_xfrags(x + (size_t)(row0 + col) * kF, h, ax0, ax1);
    bf16x8 aps0, aps1, aph0, aph1, au0, au1, ar0, ar1;
    load_wfrags(w_psi, kF, col, h, aps0, aps1); // A = W_psi^T
    load_wfrags(w_phi, kF, col, h, aph0, aph1); // A = W_phi^T
    load_wfrags(w_u,   kF, col, h, au0, au1);   // A = W_u^T
    load_wfrags(w_r,   kF, col, h, ar0, ar1);   // A = w_r^T

    f32x16 psiT = zero16(), phiT = zero16(), uT = zero16();
    psiT = MFMA(aps0, ax0, psiT); psiT = MFMA(aps1, ax1, psiT);
    phiT = MFMA(aph0, ax0, phiT); phiT = MFMA(aph1, ax1, phiT);
    uT   = MFMA(au0,  ax0, uT);   uT   = MFMA(au1,  ax1, uT);

#pragma unroll
    for (int r = 0; r < 16; ++r) {
        const int gg = (r & 3) + 8 * (r >> 2);
        psiT[r] += h ? b_psi[gg + 4] : b_psi[gg];
        phiT[r] += h ? b_phi[gg + 4] : b_phi[gg];
        uT[r] = fmaxf(uT[r] + (h ? b_u[gg + 4] : b_u[gg]), 0.f);
    }

    float d = 0.f;
#pragma unroll
    for (int r = 0; r < 16; ++r) d += psiT[r] * phiT[r];
    d += __shfl_xor(d, 32, 64);         // diag[el]

    __syncthreads();                    // m_s ready for all waves
    bf16x8 am0, am1;
    load_wfrags(m_s, 33, col, h, am0, am1);     // A = M^T (lane-varying LDS)

    bf16x8 bps0, bps1;
    c_to_kfrags(psiT, h, bps0, bps1);   // B = psi^T (K = g)
    f32x16 attT = zero16();
    attT = MFMA(am0, bps0, attT);
    attT = MFMA(am1, bps1, attT);       // col = el, row = g'

    const float inv_n = 1.0f / (float)kN;
#pragma unroll
    for (int r = 0; r < 16; ++r) attT[r] = (attT[r] - d * uT[r]) * inv_n;

    bf16x8 bt0, bt1;
    c_to_kfrags(attT, h, bt0, bt1);     // B = att'^T (K = g')
    f32x16 corrT = zero16();
    corrT = MFMA(ar0, bt0, corrT);
    corrT = MFMA(ar1, bt1, corrT);      // col = el, row = f'

    // per-wave LDS transpose then coalesced store with exact fp32 residual
    float* ts = t_s[w];
#pragma unroll
    for (int qq = 0; qq < 4; ++qq)
        *(float4*)(ts + col * 36 + 8 * qq + 4 * h) =
            make_float4(corrT[4 * qq], corrT[4 * qq + 1],
                        corrT[4 * qq + 2], corrT[4 * qq + 3]);

    const size_t gbase = (size_t)row0 * kF;
#pragma unroll
    for (int qq = 0; qq < 4; ++qq) {
        const int idx = qq * 256 + lane * 4;
        const int el = idx >> 5;
        const int cc = idx & 31;
        float4 cv = *(const float4*)(ts + el * 36 + cc);
        float4 xv = *(const float4*)(x + gbase + idx);
        *(float4*)(out + gbase + idx) =
            make_float4(xv.x + cv.x, xv.y + cv.y, xv.z + cv.z, xv.w + cv.w);
    }
}

extern "C" void kernel_launch(void* const* d_in, const int* in_sizes, int n_in,
                              void* d_out, int out_size, void* d_ws, size_t ws_size,
                              hipStream_t stream) {
    const float* x     = (const float*)d_in[0];
    const float* w_psi = (const float*)d_in[1];
    const float* b_psi = (const float*)d_in[2];
    const float* w_phi = (const float*)d_in[3];
    const float* b_phi = (const float*)d_in[4];
    const float* w_u   = (const float*)d_in[5];
    const float* b_u   = (const float*)d_in[6];
    const float* w_r   = (const float*)d_in[7];
    float* out = (float*)d_out;
    float* part = (float*)d_ws;   // 512*1024 fp32 = 2 MiB; fully written by k1
                                  // before k2 reads it -> no memset, no atomics.

    k_partial_m<<<dim3(512), 256, 0, stream>>>(x, w_phi, b_phi, w_u, b_u, part);
    k_relation<<<dim3(512), 256, 0, stream>>>(x, w_psi, b_psi, w_phi, b_phi,
                                              w_u, b_u, w_r, part, out);
}

// Round 7
// 83.050 us; speedup vs baseline: 1.0137x; 1.0137x over previous
//
#include <hip/hip_runtime.h>

// RelationModule, two kernels:
//   k1: per-wave phi/u (normal orient.), wave M-tile, 4-wave block reduce,
//       block-partial -> d_ws slot (no atomics, no memset).
//   k2: per-block reduce of its batch's 16 partials -> M[b] in LDS, then
//       transposed pipeline (C col = element), out = x + corr (fp32 residual).
//
// R7: (a) bf16 pack = round-half-up ((u+0x8000)>>16): 4 VALU/pair vs ~12 for
// manual RNE — ~60% of packing VALU gone. (b) k2 restructured so fragment
// lifetimes are sequential (peak live ~120 regs, was ~260 incl. 5 concurrent
// C-accumulators) -> real 2 waves/SIMD instead of 1 (R5's cooperative refusal
// exposed that the runtime computed <2 blocks/CU co-residency).
//
// B=32, N=2048, F=32.  bf16 MFMA v_mfma_f32_32x32x16_bf16.
// Layouts (R4-verified): C/D 32x32: col=lane&31, row=(r&3)+8*(r>>2)+4*(lane>>5)
//                        A/B frag:  m/n=lane&31, k=8*(lane>>5)+j

namespace {
constexpr int kF = 32;
constexpr int kN = 2048;
constexpr int kB = 32;
}

typedef __attribute__((ext_vector_type(8))) short bf16x8;
typedef __attribute__((ext_vector_type(16))) float f32x16;

union BF8 { bf16x8 v; int i[4]; };

// round-half-up bf16 pack: 0.5-ulp max error, 2 VALU per value.
__device__ inline int pk2(float lo, float hi) {
    union { float f; unsigned int u; } a, b;
    a.f = lo; b.f = hi;
    return (int)((a.u + 0x8000u) >> 16) | (int)((b.u + 0x8000u) & 0xFFFF0000u);
}

// Operand frags of Mat (row-major, stride ld): K = Mat rows, lane&31 = col.
// As A: Mat^T (m=col).  As B: Mat (n=col).  Global or LDS.
__device__ inline void load_wfrags(const float* __restrict__ W, int ld, int col, int h,
                                   bf16x8& f0, bf16x8& f1) {
    BF8 a, b;
#pragma unroll
    for (int q = 0; q < 4; ++q)
        a.i[q] = pk2(W[(8 * h + 2 * q) * ld + col], W[(8 * h + 2 * q + 1) * ld + col]);
#pragma unroll
    for (int q = 0; q < 4; ++q)
        b.i[q] = pk2(W[(16 + 8 * h + 2 * q) * ld + col], W[(16 + 8 * h + 2 * q + 1) * ld + col]);
    f0 = a.v; f1 = b.v;
}

// x operand: element j of fi = x[row][16*fi + 8h + j] (row = lane's element).
__device__ inline void load_xfrags(const float* __restrict__ xr, int h,
                                   bf16x8& f0, bf16x8& f1) {
    float4 a = *(const float4*)(xr + 8 * h);
    float4 b = *(const float4*)(xr + 8 * h + 4);
    float4 c = *(const float4*)(xr + 16 + 8 * h);
    float4 d = *(const float4*)(xr + 16 + 8 * h + 4);
    BF8 u0, u1;
    u0.i[0] = pk2(a.x, a.y); u0.i[1] = pk2(a.z, a.w);
    u0.i[2] = pk2(b.x, b.y); u0.i[3] = pk2(b.z, b.w);
    u1.i[0] = pk2(c.x, c.y); u1.i[1] = pk2(c.z, c.w);
    u1.i[2] = pk2(d.x, d.y); u1.i[3] = pk2(d.z, d.w);
    f0 = u0.v; f1 = u1.v;
}

// C-layout regs -> operand frags with K = C-row (col stays in lanes).
__device__ inline void c_to_kfrags(const f32x16& v, int h, bf16x8& f0, bf16x8& f1) {
    int p[8], t[8];
#pragma unroll
    for (int q = 0; q < 8; ++q) p[q] = pk2(v[2 * q], v[2 * q + 1]);
#pragma unroll
    for (int q = 0; q < 8; ++q) t[q] = __shfl_xor(p[q], 32, 64);
    BF8 a, b;
    a.i[0] = h ? t[2] : p[0];
    a.i[1] = h ? t[3] : p[1];
    a.i[2] = h ? p[2] : t[0];
    a.i[3] = h ? p[3] : t[1];
    b.i[0] = h ? t[6] : p[4];
    b.i[1] = h ? t[7] : p[5];
    b.i[2] = h ? p[6] : t[4];
    b.i[3] = h ? p[7] : t[5];
    f0 = a.v; f1 = b.v;
}

__device__ inline f32x16 zero16() {
    f32x16 z;
#pragma unroll
    for (int i = 0; i < 16; ++i) z[i] = 0.f;
    return z;
}

#define MFMA(A, B, C) __builtin_amdgcn_mfma_f32_32x32x16_bf16(A, B, C, 0, 0, 0)

// ---------------------------------------------------------------------------
// Kernel 1: block-partial M tiles. Grid 512 x 256 (4 waves, 1 batch-slice).
// ---------------------------------------------------------------------------
__global__ __launch_bounds__(256, 2) void k_partial_m(
    const float* __restrict__ x,
    const float* __restrict__ w_phi, const float* __restrict__ b_phi,
    const float* __restrict__ w_u,   const float* __restrict__ b_u,
    float* __restrict__ part)        // [512][1024] fp32, fully overwritten
{
    __shared__ float red_s[4][64 * 20];

    const int tid = threadIdx.x;
    const int lane = tid & 63;
    const int w = tid >> 6;
    const int col = lane & 31;
    const int h = lane >> 5;
    const int blk = blockIdx.x;
    const int row0 = blk * 128 + w * 32;    // 128 | 2048: block stays in-batch

    bf16x8 ax0, ax1;
    load_xfrags(x + (size_t)(row0 + col) * kF, h, ax0, ax1);

    // phi = x @ W_phi + b  (C col = g) — frags scoped for short lifetimes
    f32x16 phiC = zero16(), uC = zero16();
    {
        bf16x8 bp0, bp1;
        load_wfrags(w_phi, kF, col, h, bp0, bp1);
        phiC = MFMA(ax0, bp0, phiC); phiC = MFMA(ax1, bp1, phiC);
    }
    {
        bf16x8 bu0, bu1;
        load_wfrags(w_u, kF, col, h, bu0, bu1);
        uC = MFMA(ax0, bu0, uC); uC = MFMA(ax1, bu1, uC);
    }

    const float bphi = b_phi[col];
    const float bu = b_u[col];
#pragma unroll
    for (int r = 0; r < 16; ++r) {
        phiC[r] += bphi;
        uC[r] = fmaxf(uC[r] + bu, 0.f);
    }

    bf16x8 ap0, ap1, fu0, fu1;
    c_to_kfrags(phiC, h, ap0, ap1);     // A = phi^T (K = element); phiC dead
    c_to_kfrags(uC, h, fu0, fu1);       // B = u; uC dead
    f32x16 macc = zero16();
    macc = MFMA(ap0, fu0, macc);
    macc = MFMA(ap1, fu1, macc);        // C: col = g, row = f

    float* rs = red_s[w] + lane * 20;
#pragma unroll
    for (int q = 0; q < 4; ++q)
        *(float4*)(rs + 4 * q) = make_float4(macc[4 * q], macc[4 * q + 1],
                                             macc[4 * q + 2], macc[4 * q + 3]);
    __syncthreads();

    const int lp = tid >> 2;
    const int q = tid & 3;
    float4 s = make_float4(0.f, 0.f, 0.f, 0.f);
#pragma unroll
    for (int ww = 0; ww < 4; ++ww) {
        float4 v = *(const float4*)(red_s[ww] + lp * 20 + 4 * q);
        s.x += v.x; s.y += v.y; s.z += v.z; s.w += v.w;
    }
    // coalesced store in "reduced-C order"; k2 applies the same (lp,q) map
    *(float4*)(part + (size_t)blk * 1024 + tid * 4) = s;
}

// ---------------------------------------------------------------------------
// Kernel 2: M[b] reduce + transposed relation pipeline. Grid 512 x 256.
// Fragment lifetimes strictly sequential to stay under 2-waves/SIMD regs.
// ---------------------------------------------------------------------------
__global__ __launch_bounds__(256, 2) void k_relation(
    const float* __restrict__ x,
    const float* __restrict__ w_psi, const float* __restrict__ b_psi,
    const float* __restrict__ w_phi, const float* __restrict__ b_phi,
    const float* __restrict__ w_u,   const float* __restrict__ b_u,
    const float* __restrict__ w_r,
    const float* __restrict__ part,  // [512][1024] block partials from k1
    float* __restrict__ out)
{
    __shared__ float t_s[4][32 * 36];   // per-wave transpose scratch
    __shared__ float m_s[kF * 33];      // M[b], row stride 33

    const int tid = threadIdx.x;
    const int lane = tid & 63;
    const int w = tid >> 6;
    const int col = lane & 31;
    const int h = lane >> 5;
    const int blk = blockIdx.x;
    const int row0 = blk * 128 + w * 32;
    const int b = blk >> 4;

    // ---- M[b] = sum of this batch's 16 partials (coalesced, L2/L3-fed) ----
    {
        const float* pb = part + (size_t)(b * 16) * 1024 + tid * 4;
        float4 ms = make_float4(0.f, 0.f, 0.f, 0.f);
#pragma unroll
        for (int p = 0; p < 16; ++p) {
            float4 v = *(const float4*)(pb + p * 1024);
            ms.x += v.x; ms.y += v.y; ms.z += v.z; ms.w += v.w;
        }
        const int lp = tid >> 2;
        const int q = tid & 3;
        const int g = lp & 31;
        const int f0 = 8 * q + 4 * (lp >> 5);
        m_s[(f0 + 0) * 33 + g] = ms.x;
        m_s[(f0 + 1) * 33 + g] = ms.y;
        m_s[(f0 + 2) * 33 + g] = ms.z;
        m_s[(f0 + 3) * 33 + g] = ms.w;
    }

    bf16x8 ax0, ax1;
    load_xfrags(x + (size_t)(row0 + col) * kF, h, ax0, ax1);

    // psi^T = W_psi^T @ x^T
    f32x16 psiT = zero16();
    {
        bf16x8 a0, a1;
        load_wfrags(w_psi, kF, col, h, a0, a1);
        psiT = MFMA(a0, ax0, psiT); psiT = MFMA(a1, ax1, psiT);
    }
    // phi^T — lives only until diag
    float d;
    {
        f32x16 phiT = zero16();
        bf16x8 a0, a1;
        load_wfrags(w_phi, kF, col, h, a0, a1);
        phiT = MFMA(a0, ax0, phiT); phiT = MFMA(a1, ax1, phiT);
        d = 0.f;
#pragma unroll
        for (int r = 0; r < 16; ++r) {
            const int gg = (r & 3) + 8 * (r >> 2);
            psiT[r] += h ? b_psi[gg + 4] : b_psi[gg];
            const float phv = phiT[r] + (h ? b_phi[gg + 4] : b_phi[gg]);
            d += psiT[r] * phv;
        }
        d += __shfl_xor(d, 32, 64);     // diag[el]; phiT dead here
    }
    // u^T (reuses phiT's registers)
    f32x16 uT = zero16();
    {
        bf16x8 a0, a1;
        load_wfrags(w_u, kF, col, h, a0, a1);
        uT = MFMA(a0, ax0, uT); uT = MFMA(a1, ax1, uT);
#pragma unroll
        for (int r = 0; r < 16; ++r) {
            const int gg = (r & 3) + 8 * (r >> 2);
            uT[r] = fmaxf(uT[r] + (h ? b_u[gg + 4] : b_u[gg]), 0.f);
        }
    }
    // ax dead from here on.

    // att^T = M^T @ psi^T
    f32x16 attT = zero16();
    {
        bf16x8 bps0, bps1;
        c_to_kfrags(psiT, h, bps0, bps1);   // B = psi^T (K = g); psiT dead
        __syncthreads();                    // m_s ready for all waves
        bf16x8 am0, am1;
        load_wfrags(m_s, 33, col, h, am0, am1);
        attT = MFMA(am0, bps0, attT);
        attT = MFMA(am1, bps1, attT);       // col = el, row = g'
    }

    const float inv_n = 1.0f / (float)kN;
#pragma unroll
    for (int r = 0; r < 16; ++r) attT[r] = (attT[r] - d * uT[r]) * inv_n;
    // uT dead.

    // corr^T = w_r^T @ att'^T
    f32x16 corrT = zero16();
    {
        bf16x8 bt0, bt1;
        c_to_kfrags(attT, h, bt0, bt1);     // attT dead
        bf16x8 a0, a1;
        load_wfrags(w_r, kF, col, h, a0, a1);
        corrT = MFMA(a0, bt0, corrT);
        corrT = MFMA(a1, bt1, corrT);       // col = el, row = f'
    }

    // per-wave LDS transpose then coalesced store with exact fp32 residual
    float* ts = t_s[w];
#pragma unroll
    for (int qq = 0; qq < 4; ++qq)
        *(float4*)(ts + col * 36 + 8 * qq + 4 * h) =
            make_float4(corrT[4 * qq], corrT[4 * qq + 1],
                        corrT[4 * qq + 2], corrT[4 * qq + 3]);

    const size_t gbase = (size_t)row0 * kF;
#pragma unroll
    for (int qq = 0; qq < 4; ++qq) {
        const int idx = qq * 256 + lane * 4;
        const int el = idx >> 5;
        const int cc = idx & 31;
        float4 cv = *(const float4*)(ts + el * 36 + cc);
        float4 xv = *(const float4*)(x + gbase + idx);
        *(float4*)(out + gbase + idx) =
            make_float4(xv.x + cv.x, xv.y + cv.y, xv.z + cv.z, xv.w + cv.w);
    }
}

extern "C" void kernel_launch(void* const* d_in, const int* in_sizes, int n_in,
                              void* d_out, int out_size, void* d_ws, size_t ws_size,
                              hipStream_t stream) {
    const float* x     = (const float*)d_in[0];
    const float* w_psi = (const float*)d_in[1];
    const float* b_psi = (const float*)d_in[2];
    const float* w_phi = (const float*)d_in[3];
    const float* b_phi = (const float*)d_in[4];
    const float* w_u   = (const float*)d_in[5];
    const float* b_u   = (const float*)d_in[6];
    const float* w_r   = (const float*)d_in[7];
    float* out = (float*)d_out;
    float* part = (float*)d_ws;   // 512*1024 fp32 = 2 MiB; fully written by k1
                                  // before k2 reads it -> no memset, no atomics.

    k_partial_m<<<dim3(512), 256, 0, stream>>>(x, w_phi, b_phi, w_u, b_u, part);
    k_relation<<<dim3(512), 256, 0, stream>>>(x, w_psi, b_psi, w_phi, b_phi,
                                              w_u, b_u, w_r, part, out);
}